// Round 10
// baseline (497.408 us; speedup 1.0000x reference)
//
#include <hip/hip_runtime.h>

#define NN 50000
#define NE 800000
#define F 256
#define NHEADS 8

typedef __attribute__((ext_vector_type(8))) short bf16x8;
typedef __attribute__((ext_vector_type(4))) float f32x4;

__device__ __forceinline__ unsigned short f2bf_rn(float f) {
  unsigned u = __float_as_uint(f);
  u += 0x7fff + ((u >> 16) & 1);
  return (unsigned short)(u >> 16);
}
__device__ __forceinline__ float bf2f(unsigned short b) {
  return __uint_as_float(((unsigned)b) << 16);
}
__device__ __forceinline__ float h2f(unsigned short h) {
  _Float16 f;
  __builtin_memcpy(&f, &h, 2);
  return (float)f;
}
__device__ __forceinline__ unsigned short f2h(float x) {
  _Float16 f = (_Float16)x;
  unsigned short u;
  __builtin_memcpy(&u, &f, 2);
  return u;
}
// load 4 consecutive fp16 -> float4 (8B aligned)
__device__ __forceinline__ float4 ld_h4(const unsigned short* p) {
  unsigned long long u = *reinterpret_cast<const unsigned long long*>(p);
  return make_float4(h2f((unsigned short)u), h2f((unsigned short)(u >> 16)),
                     h2f((unsigned short)(u >> 32)), h2f((unsigned short)(u >> 48)));
}

__device__ __forceinline__ void gld16(const unsigned short* g, unsigned short* l) {
  __builtin_amdgcn_global_load_lds(
      (const __attribute__((address_space(1))) unsigned int*)g,
      (__attribute__((address_space(3))) unsigned int*)l, 16, 0, 0);
}

// ---------------- CSR build (dst-sorted) ----------------
__global__ void k_zero_int(int* __restrict__ p, int n) {
  int i = blockIdx.x * blockDim.x + threadIdx.x;
  if (i < n) p[i] = 0;
}

__global__ void k_hist(const int* __restrict__ dst, int* __restrict__ counts, int e) {
  int i = blockIdx.x * blockDim.x + threadIdx.x;
  if (i < e) atomicAdd(&counts[dst[i]], 1);
}

__global__ __launch_bounds__(256) void k_blocksum(const int* __restrict__ counts,
                                                  int* __restrict__ bsum, int n) {
  int i = blockIdx.x * 256 + threadIdx.x;
  int v = (i < n) ? counts[i] : 0;
#pragma unroll
  for (int d = 32; d >= 1; d >>= 1) v += __shfl_xor(v, d, 64);
  __shared__ int sdata[4];
  if ((threadIdx.x & 63) == 0) sdata[threadIdx.x >> 6] = v;
  __syncthreads();
  if (threadIdx.x == 0) bsum[blockIdx.x] = sdata[0] + sdata[1] + sdata[2] + sdata[3];
}

__global__ __launch_bounds__(256) void k_scan_bsums(int* __restrict__ bsum,
                                                    int* __restrict__ off, int nb, int n) {
  __shared__ int buf[256];
  const int tid = threadIdx.x;
  int v = (tid < nb) ? bsum[tid] : 0;
  buf[tid] = v;
  __syncthreads();
  for (int d = 1; d < 256; d <<= 1) {
    int t = (tid >= d) ? buf[tid - d] : 0;
    __syncthreads();
    buf[tid] += t;
    __syncthreads();
  }
  if (tid < nb) bsum[tid] = buf[tid] - v;  // exclusive
  if (tid == 255) off[n] = buf[255];
}

__global__ __launch_bounds__(256) void k_scan_final(int* __restrict__ counts,
                                                    const int* __restrict__ bsum,
                                                    int* __restrict__ off, int n) {
  __shared__ int buf[256];
  const int tid = threadIdx.x;
  const int i = blockIdx.x * 256 + tid;
  int v = (i < n) ? counts[i] : 0;
  buf[tid] = v;
  __syncthreads();
  for (int d = 1; d < 256; d <<= 1) {
    int t = (tid >= d) ? buf[tid - d] : 0;
    __syncthreads();
    buf[tid] += t;
    __syncthreads();
  }
  if (i < n) {
    off[i] = bsum[blockIdx.x] + buf[tid] - v;
    counts[i] = 0;  // reuse as scatter cursor
  }
}

__global__ void k_scatter(const int* __restrict__ src, const int* __restrict__ dst,
                          const int* __restrict__ off, int* __restrict__ cursor,
                          int* __restrict__ csr_src, int e) {
  int i = blockIdx.x * blockDim.x + threadIdx.x;
  if (i < e) {
    int d = dst[i];
    int p = atomicAdd(&cursor[d], 1);
    csr_src[off[d] + p] = src[i];
  }
}

// ---------------- f32 -> bf16 hi/lo split (layer-0 input only) ----------------
__global__ void k_split(const float* __restrict__ x, unsigned short* __restrict__ hi,
                        unsigned short* __restrict__ lo, int n8) {
  int i = blockIdx.x * blockDim.x + threadIdx.x;
  if (i >= n8) return;
  const float4* xp = reinterpret_cast<const float4*>(x) + (size_t)i * 2;
  float4 a = xp[0], b = xp[1];
  float v[8] = {a.x, a.y, a.z, a.w, b.x, b.y, b.z, b.w};
  unsigned short hv[8], lv[8];
#pragma unroll
  for (int j = 0; j < 8; ++j) {
    hv[j] = f2bf_rn(v[j]);
    lv[j] = f2bf_rn(v[j] - bf2f(hv[j]));
  }
  uint4 ho, lo4;
  ho.x = (unsigned)hv[0] | ((unsigned)hv[1] << 16);
  ho.y = (unsigned)hv[2] | ((unsigned)hv[3] << 16);
  ho.z = (unsigned)hv[4] | ((unsigned)hv[5] << 16);
  ho.w = (unsigned)hv[6] | ((unsigned)hv[7] << 16);
  lo4.x = (unsigned)lv[0] | ((unsigned)lv[1] << 16);
  lo4.y = (unsigned)lv[2] | ((unsigned)lv[3] << 16);
  lo4.z = (unsigned)lv[4] | ((unsigned)lv[5] << 16);
  lo4.w = (unsigned)lv[6] | ((unsigned)lv[7] << 16);
  *reinterpret_cast<uint4*>(&hi[(size_t)i * 8]) = ho;
  *reinterpret_cast<uint4*>(&lo[(size_t)i * 8]) = lo4;
}

// W[l] is [K=256][N=256] row-major; produce transposed bf16 hi/lo: Wt[n][k]
__global__ void k_wsplit(const float* __restrict__ W, unsigned short* __restrict__ Whi,
                         unsigned short* __restrict__ Wlo) {
  int i = blockIdx.x * 256 + threadIdx.x;  // i = n*256 + k
  int n = i >> 8, k = i & 255;
  float v = W[k * 256 + n];
  unsigned short h = f2bf_rn(v);
  Whi[i] = h;
  Wlo[i] = f2bf_rn(v - bf2f(h));
}

// ---------------- split-bf16 MFMA GEMM + fused el/er epilogue ----------------
// 128x256 tile (FULL N): A panel fetched once per layer; 391 blocks (half the
// prologue count). 512 threads = 8 waves (2 row x 4 col), each wave 64x64 out.
// BK=32, 8 K-steps, round-6 2-barrier gld16 staging. LDS 48KB (~3 blocks/CU).
__global__ __launch_bounds__(512) void k_gemm_mfma(
    const unsigned short* __restrict__ Ahi, const unsigned short* __restrict__ Alo,
    const unsigned short* __restrict__ Bhi, const unsigned short* __restrict__ Blo,
    const float* __restrict__ al, const float* __restrict__ ar,
    unsigned short* __restrict__ h2, float* __restrict__ el, float* __restrict__ er,
    int M)
{
  __shared__ unsigned short sAh[128 * 32];
  __shared__ unsigned short sAl[128 * 32];
  __shared__ unsigned short sBh[256 * 32];
  __shared__ unsigned short sBl[256 * 32];
  const int tid = threadIdx.x;
  const int w = tid >> 6, lane = tid & 63;
  const int row0 = blockIdx.x * 128;
  const int wr = w >> 2, wc = w & 3;   // 2x4 wave grid; wave = 64 rows x 64 cols

  f32x4 acc[4][4];
#pragma unroll
  for (int i = 0; i < 4; ++i)
#pragma unroll
    for (int j = 0; j < 4; ++j) acc[i][j] = (f32x4)0.0f;

  const int l15 = lane & 15;
  const int lq = lane >> 4;
  const int lk = lq * 8;

  // per-step staging: 6 gld16/thread. Regions (512 units of 16B each):
  // Ah | Al | Bh rows 0-127 | Bh rows 128-255 | Bl rows 0-127 | Bl rows 128-255
  const int r4 = tid >> 2, ku = tid & 3;
  const int wb = w * 512;  // wave-uniform elem base within a region

  for (int step = 0; step < 8; ++step) {
    const int k0 = step * 32;
    __syncthreads();
    {
      const int arow = min(row0 + r4, M - 1);
      const size_t aoff = (size_t)arow * F + k0 + ku * 8;
      gld16(Ahi + aoff, &sAh[wb]);
      gld16(Alo + aoff, &sAl[wb]);
      const size_t b0off = (size_t)r4 * F + k0 + ku * 8;
      gld16(Bhi + b0off, &sBh[wb]);
      gld16(Blo + b0off, &sBl[wb]);
      const size_t b1off = (size_t)(128 + r4) * F + k0 + ku * 8;
      gld16(Bhi + b1off, &sBh[4096 + wb]);
      gld16(Blo + b1off, &sBl[4096 + wb]);
    }
    __syncthreads();

    bf16x8 ah[4], alv[4], bh[4], bl[4];
#pragma unroll
    for (int f = 0; f < 4; ++f) {
      const int ra = (wr * 64 + f * 16 + l15) * 32 + lk;
      const int rb = (wc * 64 + f * 16 + l15) * 32 + lk;
      ah[f]  = *reinterpret_cast<const bf16x8*>(&sAh[ra]);
      alv[f] = *reinterpret_cast<const bf16x8*>(&sAl[ra]);
      bh[f]  = *reinterpret_cast<const bf16x8*>(&sBh[rb]);
      bl[f]  = *reinterpret_cast<const bf16x8*>(&sBl[rb]);
    }
#pragma unroll
    for (int fr = 0; fr < 4; ++fr)
#pragma unroll
      for (int fc = 0; fc < 4; ++fc) {
        acc[fr][fc] = __builtin_amdgcn_mfma_f32_16x16x32_bf16(ah[fr], bh[fc], acc[fr][fc], 0, 0, 0);
        acc[fr][fc] = __builtin_amdgcn_mfma_f32_16x16x32_bf16(ah[fr], bl[fc], acc[fr][fc], 0, 0, 0);
        acc[fr][fc] = __builtin_amdgcn_mfma_f32_16x16x32_bf16(alv[fr], bh[fc], acc[fr][fc], 0, 0, 0);
      }
  }

  // ---- h2 (fp16, row-major) store ----
#pragma unroll
  for (int fr = 0; fr < 4; ++fr) {
#pragma unroll
    for (int r = 0; r < 4; ++r) {
      const int grow = row0 + wr * 64 + fr * 16 + lq * 4 + r;
      if (grow < M) {
#pragma unroll
        for (int fc = 0; fc < 4; ++fc)
          h2[(size_t)grow * F + wc * 64 + fc * 16 + l15] = f2h(acc[fr][fc][r]);
      }
    }
  }

  // ---- fused el/er: exact f32 dot with al/ar over this wave's 64 cols (2 heads) ----
  float alc[4], arc[4];
#pragma unroll
  for (int fc = 0; fc < 4; ++fc) {
    const int cg = wc * 64 + fc * 16 + l15;
    alc[fc] = al[cg];
    arc[fc] = ar[cg];
  }
  const int hb = wc * 2;
#pragma unroll
  for (int fr = 0; fr < 4; ++fr) {
#pragma unroll
    for (int r = 0; r < 4; ++r) {
      float e0 = acc[fr][0][r] * alc[0] + acc[fr][1][r] * alc[1];
      float e1 = acc[fr][2][r] * alc[2] + acc[fr][3][r] * alc[3];
      float f0 = acc[fr][0][r] * arc[0] + acc[fr][1][r] * arc[1];
      float f1 = acc[fr][2][r] * arc[2] + acc[fr][3][r] * arc[3];
#pragma unroll
      for (int d = 1; d < 16; d <<= 1) {
        e0 += __shfl_xor(e0, d, 64);
        e1 += __shfl_xor(e1, d, 64);
        f0 += __shfl_xor(f0, d, 64);
        f1 += __shfl_xor(f1, d, 64);
      }
      const int n = row0 + wr * 64 + fr * 16 + lq * 4 + r;
      if (l15 == 0 && n < M) {
        el[n * 8 + hb] = e0;
        el[n * 8 + hb + 1] = e1;
        er[n * 8 + hb] = f0;
        er[n * 8 + hb + 1] = f1;
      }
    }
  }
}

// ---------------- fused aggregation: one wave per dst node, single edge pass ----
// (round-6 structure: ~82us, ~20% above the measured L2-miss fabric floor; done)
__global__ __launch_bounds__(512) void k_agg(
    const unsigned short* __restrict__ h2, const float* __restrict__ el,
    const float* __restrict__ er, const int* __restrict__ off,
    const int* __restrict__ csr_src, const float* __restrict__ bias,
    float* __restrict__ yf, unsigned short* __restrict__ yhi,
    unsigned short* __restrict__ ylo, int mode)  // mode 0: bf16 hi/lo + leaky; 1: f32 final
{
  __shared__ float a_lds[8][64][9];  // pad 8->9: conflict-free write & read
  __shared__ int s_lds[8][64];
  const int wave = threadIdx.x >> 6;
  const int lane = threadIdx.x & 63;
  const int n = blockIdx.x * 8 + wave;
  if (n >= NN) return;
  const int o0 = off[n], o1 = off[n + 1];

  float ern[8];
  {
    const float4 e0 = *reinterpret_cast<const float4*>(&er[n * 8]);
    const float4 e1 = *reinterpret_cast<const float4*>(&er[n * 8 + 4]);
    ern[0] = e0.x; ern[1] = e0.y; ern[2] = e0.z; ern[3] = e0.w;
    ern[4] = e1.x; ern[5] = e1.y; ern[6] = e1.z; ern[7] = e1.w;
  }
  const int c0 = lane * 4;
  const int myh = lane >> 3;
  float asum = 0.f;  // per-lane sum of exp for head myh (all edges)
  float4 acc0 = make_float4(0.f, 0.f, 0.f, 0.f), acc1 = acc0, acc2 = acc0, acc3 = acc0;

  for (int start = o0; start < o1; start += 64) {
    const int idx = start + lane;
    if (idx < o1) {
      const int s = csr_src[idx];
      s_lds[wave][lane] = s;
      const float4 e0 = *reinterpret_cast<const float4*>(&el[s * 8]);
      const float4 e1 = *reinterpret_cast<const float4*>(&el[s * 8 + 4]);
      float ev[8] = {e0.x, e0.y, e0.z, e0.w, e1.x, e1.y, e1.z, e1.w};
#pragma unroll
      for (int t = 0; t < 8; ++t) {
        float e = ev[t] + ern[t];
        e = e > 0.f ? e : 0.2f * e;
        a_lds[wave][lane][t] = __expf(e);
      }
    }
    // same-wave LDS RAW ordering
    asm volatile("s_waitcnt lgkmcnt(0)" ::: "memory");
    __builtin_amdgcn_sched_barrier(0);
    const int cnt = min(64, o1 - start);
    int k = 0;
    for (; k + 8 <= cnt; k += 8) {
      const int s0 = s_lds[wave][k + 0], s1 = s_lds[wave][k + 1];
      const int s2 = s_lds[wave][k + 2], s3 = s_lds[wave][k + 3];
      const int s4 = s_lds[wave][k + 4], s5 = s_lds[wave][k + 5];
      const int s6 = s_lds[wave][k + 6], s7 = s_lds[wave][k + 7];
      const float a0 = a_lds[wave][k + 0][myh], a1 = a_lds[wave][k + 1][myh];
      const float a2 = a_lds[wave][k + 2][myh], a3 = a_lds[wave][k + 3][myh];
      const float a4 = a_lds[wave][k + 4][myh], a5 = a_lds[wave][k + 5][myh];
      const float a6 = a_lds[wave][k + 6][myh], a7 = a_lds[wave][k + 7][myh];
      const float4 h0 = ld_h4(&h2[(size_t)s0 * F + c0]);
      const float4 h1 = ld_h4(&h2[(size_t)s1 * F + c0]);
      const float4 h2v = ld_h4(&h2[(size_t)s2 * F + c0]);
      const float4 h3 = ld_h4(&h2[(size_t)s3 * F + c0]);
      const float4 h4 = ld_h4(&h2[(size_t)s4 * F + c0]);
      const float4 h5 = ld_h4(&h2[(size_t)s5 * F + c0]);
      const float4 h6 = ld_h4(&h2[(size_t)s6 * F + c0]);
      const float4 h7 = ld_h4(&h2[(size_t)s7 * F + c0]);
      asum += ((a0 + a1) + (a2 + a3)) + ((a4 + a5) + (a6 + a7));
      acc0.x = fmaf(a0, h0.x, acc0.x); acc0.y = fmaf(a0, h0.y, acc0.y);
      acc0.z = fmaf(a0, h0.z, acc0.z); acc0.w = fmaf(a0, h0.w, acc0.w);
      acc1.x = fmaf(a1, h1.x, acc1.x); acc1.y = fmaf(a1, h1.y, acc1.y);
      acc1.z = fmaf(a1, h1.z, acc1.z); acc1.w = fmaf(a1, h1.w, acc1.w);
      acc2.x = fmaf(a2, h2v.x, acc2.x); acc2.y = fmaf(a2, h2v.y, acc2.y);
      acc2.z = fmaf(a2, h2v.z, acc2.z); acc2.w = fmaf(a2, h2v.w, acc2.w);
      acc3.x = fmaf(a3, h3.x, acc3.x); acc3.y = fmaf(a3, h3.y, acc3.y);
      acc3.z = fmaf(a3, h3.z, acc3.z); acc3.w = fmaf(a3, h3.w, acc3.w);
      acc0.x = fmaf(a4, h4.x, acc0.x); acc0.y = fmaf(a4, h4.y, acc0.y);
      acc0.z = fmaf(a4, h4.z, acc0.z); acc0.w = fmaf(a4, h4.w, acc0.w);
      acc1.x = fmaf(a5, h5.x, acc1.x); acc1.y = fmaf(a5, h5.y, acc1.y);
      acc1.z = fmaf(a5, h5.z, acc1.z); acc1.w = fmaf(a5, h5.w, acc1.w);
      acc2.x = fmaf(a6, h6.x, acc2.x); acc2.y = fmaf(a6, h6.y, acc2.y);
      acc2.z = fmaf(a6, h6.z, acc2.z); acc2.w = fmaf(a6, h6.w, acc2.w);
      acc3.x = fmaf(a7, h7.x, acc3.x); acc3.y = fmaf(a7, h7.y, acc3.y);
      acc3.z = fmaf(a7, h7.z, acc3.z); acc3.w = fmaf(a7, h7.w, acc3.w);
    }
    for (; k < cnt; ++k) {
      const int s = s_lds[wave][k];
      const float a = a_lds[wave][k][myh];
      const float4 hv = ld_h4(&h2[(size_t)s * F + c0]);
      asum += a;
      acc0.x = fmaf(a, hv.x, acc0.x); acc0.y = fmaf(a, hv.y, acc0.y);
      acc0.z = fmaf(a, hv.z, acc0.z); acc0.w = fmaf(a, hv.w, acc0.w);
    }
    __builtin_amdgcn_sched_barrier(0);
  }

  const float inv = asum > 0.f ? 1.f / asum : 0.f;

  const float4 bv = *reinterpret_cast<const float4*>(&bias[c0]);
  float4 o;
  o.x = (acc0.x + acc1.x + acc2.x + acc3.x) * inv + bv.x;
  o.y = (acc0.y + acc1.y + acc2.y + acc3.y) * inv + bv.y;
  o.z = (acc0.z + acc1.z + acc2.z + acc3.z) * inv + bv.z;
  o.w = (acc0.w + acc1.w + acc2.w + acc3.w) * inv + bv.w;
  if (mode == 0) {
    o.x = o.x > 0.f ? o.x : 0.01f * o.x;
    o.y = o.y > 0.f ? o.y : 0.01f * o.y;
    o.z = o.z > 0.f ? o.z : 0.01f * o.z;
    o.w = o.w > 0.f ? o.w : 0.01f * o.w;
    unsigned short h0 = f2bf_rn(o.x), h1 = f2bf_rn(o.y), h2w = f2bf_rn(o.z), h3 = f2bf_rn(o.w);
    unsigned short l0 = f2bf_rn(o.x - bf2f(h0)), l1 = f2bf_rn(o.y - bf2f(h1));
    unsigned short l2 = f2bf_rn(o.z - bf2f(h2w)), l3 = f2bf_rn(o.w - bf2f(h3));
    uint2 hw, lw;
    hw.x = (unsigned)h0 | ((unsigned)h1 << 16); hw.y = (unsigned)h2w | ((unsigned)h3 << 16);
    lw.x = (unsigned)l0 | ((unsigned)l1 << 16); lw.y = (unsigned)l2 | ((unsigned)l3 << 16);
    *reinterpret_cast<uint2*>(&yhi[(size_t)n * F + c0]) = hw;
    *reinterpret_cast<uint2*>(&ylo[(size_t)n * F + c0]) = lw;
  } else {
    *reinterpret_cast<float4*>(&yf[(size_t)n * F + c0]) = o;
  }
}

extern "C" void kernel_launch(void* const* d_in, const int* in_sizes, int n_in,
                              void* d_out, int out_size, void* d_ws, size_t ws_size,
                              hipStream_t stream) {
  const float* x   = (const float*)d_in[0];
  const int*   src = (const int*)d_in[1];
  const int*   dst = (const int*)d_in[2];
  const float* W   = (const float*)d_in[3];
  const float* al  = (const float*)d_in[4];
  const float* ar  = (const float*)d_in[5];
  const float* b   = (const float*)d_in[6];
  float* out = (float*)d_out;

  char* ws = (char*)d_ws;
  auto take = [&](size_t bytes) {
    char* p = ws;
    ws += (bytes + 255) & ~(size_t)255;
    return p;
  };
  int*   off     = (int*)take((NN + 1) * sizeof(int));
  int*   counts  = (int*)take(NN * sizeof(int));
  int*   bsum    = (int*)take(256 * sizeof(int));
  int*   csr_src = (int*)take(NE * sizeof(int));
  float* el      = (float*)take((size_t)NN * NHEADS * sizeof(float));
  float* er      = (float*)take((size_t)NN * NHEADS * sizeof(float));
  unsigned short* h2    = (unsigned short*)take((size_t)NN * F * 2);
  unsigned short* A_hi  = (unsigned short*)take((size_t)NN * F * 2);
  unsigned short* A_lo  = (unsigned short*)take((size_t)NN * F * 2);
  unsigned short* Wt_hi = (unsigned short*)take((size_t)F * F * 2);
  unsigned short* Wt_lo = (unsigned short*)take((size_t)F * F * 2);

  // CSR build
  const int NB = (NN + 255) / 256;  // 196
  k_zero_int<<<NB, 256, 0, stream>>>(counts, NN);
  k_hist<<<(NE + 255) / 256, 256, 0, stream>>>(dst, counts, NE);
  k_blocksum<<<NB, 256, 0, stream>>>(counts, bsum, NN);
  k_scan_bsums<<<1, 256, 0, stream>>>(bsum, off, NB, NN);
  k_scan_final<<<NB, 256, 0, stream>>>(counts, bsum, off, NN);
  k_scatter<<<(NE + 255) / 256, 256, 0, stream>>>(src, dst, off, counts, csr_src, NE);

  const int n8 = NN * F / 8;
  k_split<<<(n8 + 255) / 256, 256, 0, stream>>>(x, A_hi, A_lo, n8);
  const int nrblk = (NN + 127) / 128;  // 391
  for (int l = 0; l < 3; ++l) {
    k_wsplit<<<256, 256, 0, stream>>>(W + (size_t)l * F * F, Wt_hi, Wt_lo);
    k_gemm_mfma<<<nrblk, 512, 0, stream>>>(
        A_hi, A_lo, Wt_hi, Wt_lo, al + l * F, ar + l * F, h2, el, er, NN);
    // layers 0,1: write next-layer bf16 hi/lo input; layer 2: final f32 to d_out
    k_agg<<<(NN + 7) / 8, 512, 0, stream>>>(h2, el, er, off, csr_src, b + (size_t)l * F,
                                            out, A_hi, A_lo, (l < 2) ? 0 : 1);
  }
}

// Round 11
// 452.535 us; speedup vs baseline: 1.0992x; 1.0992x over previous
//
#include <hip/hip_runtime.h>

#define NN 50000
#define NE 800000
#define F 256
#define NHEADS 8

typedef __attribute__((ext_vector_type(8))) _Float16 f16x8;
typedef __attribute__((ext_vector_type(4))) float f32x4;

__device__ __forceinline__ float h2f(unsigned short h) {
  _Float16 f;
  __builtin_memcpy(&f, &h, 2);
  return (float)f;
}
__device__ __forceinline__ unsigned short f2h(float x) {
  _Float16 f = (_Float16)x;
  unsigned short u;
  __builtin_memcpy(&u, &f, 2);
  return u;
}
// load 4 consecutive fp16 -> float4 (8B aligned)
__device__ __forceinline__ float4 ld_h4(const unsigned short* p) {
  unsigned long long u = *reinterpret_cast<const unsigned long long*>(p);
  return make_float4(h2f((unsigned short)u), h2f((unsigned short)(u >> 16)),
                     h2f((unsigned short)(u >> 32)), h2f((unsigned short)(u >> 48)));
}

__device__ __forceinline__ void gld16(const unsigned short* g, unsigned short* l) {
  __builtin_amdgcn_global_load_lds(
      (const __attribute__((address_space(1))) unsigned int*)g,
      (__attribute__((address_space(3))) unsigned int*)l, 16, 0, 0);
}

// ---------------- CSR build (dst-sorted) ----------------
__global__ void k_zero_int(int* __restrict__ p, int n) {
  int i = blockIdx.x * blockDim.x + threadIdx.x;
  if (i < n) p[i] = 0;
}

__global__ void k_hist(const int* __restrict__ dst, int* __restrict__ counts, int e) {
  int i = blockIdx.x * blockDim.x + threadIdx.x;
  if (i < e) atomicAdd(&counts[dst[i]], 1);
}

__global__ __launch_bounds__(256) void k_blocksum(const int* __restrict__ counts,
                                                  int* __restrict__ bsum, int n) {
  int i = blockIdx.x * 256 + threadIdx.x;
  int v = (i < n) ? counts[i] : 0;
#pragma unroll
  for (int d = 32; d >= 1; d >>= 1) v += __shfl_xor(v, d, 64);
  __shared__ int sdata[4];
  if ((threadIdx.x & 63) == 0) sdata[threadIdx.x >> 6] = v;
  __syncthreads();
  if (threadIdx.x == 0) bsum[blockIdx.x] = sdata[0] + sdata[1] + sdata[2] + sdata[3];
}

__global__ __launch_bounds__(256) void k_scan_bsums(int* __restrict__ bsum,
                                                    int* __restrict__ off, int nb, int n) {
  __shared__ int buf[256];
  const int tid = threadIdx.x;
  int v = (tid < nb) ? bsum[tid] : 0;
  buf[tid] = v;
  __syncthreads();
  for (int d = 1; d < 256; d <<= 1) {
    int t = (tid >= d) ? buf[tid - d] : 0;
    __syncthreads();
    buf[tid] += t;
    __syncthreads();
  }
  if (tid < nb) bsum[tid] = buf[tid] - v;  // exclusive
  if (tid == 255) off[n] = buf[255];
}

__global__ __launch_bounds__(256) void k_scan_final(int* __restrict__ counts,
                                                    const int* __restrict__ bsum,
                                                    int* __restrict__ off, int n) {
  __shared__ int buf[256];
  const int tid = threadIdx.x;
  const int i = blockIdx.x * 256 + tid;
  int v = (i < n) ? counts[i] : 0;
  buf[tid] = v;
  __syncthreads();
  for (int d = 1; d < 256; d <<= 1) {
    int t = (tid >= d) ? buf[tid - d] : 0;
    __syncthreads();
    buf[tid] += t;
    __syncthreads();
  }
  if (i < n) {
    off[i] = bsum[blockIdx.x] + buf[tid] - v;
    counts[i] = 0;  // reuse as scatter cursor
  }
}

__global__ void k_scatter(const int* __restrict__ src, const int* __restrict__ dst,
                          const int* __restrict__ off, int* __restrict__ cursor,
                          int* __restrict__ csr_src, int e) {
  int i = blockIdx.x * blockDim.x + threadIdx.x;
  if (i < e) {
    int d = dst[i];
    int p = atomicAdd(&cursor[d], 1);
    csr_src[off[d] + p] = src[i];
  }
}

// ---------------- f32 -> fp16 hi/lo split (layer-0 input only) ----------------
__global__ void k_split(const float* __restrict__ x, unsigned short* __restrict__ hi,
                        unsigned short* __restrict__ lo, int n8) {
  int i = blockIdx.x * blockDim.x + threadIdx.x;
  if (i >= n8) return;
  const float4* xp = reinterpret_cast<const float4*>(x) + (size_t)i * 2;
  float4 a = xp[0], b = xp[1];
  float v[8] = {a.x, a.y, a.z, a.w, b.x, b.y, b.z, b.w};
  unsigned short hv[8], lv[8];
#pragma unroll
  for (int j = 0; j < 8; ++j) {
    hv[j] = f2h(v[j]);
    lv[j] = f2h(v[j] - h2f(hv[j]));
  }
  uint4 ho, lo4;
  ho.x = (unsigned)hv[0] | ((unsigned)hv[1] << 16);
  ho.y = (unsigned)hv[2] | ((unsigned)hv[3] << 16);
  ho.z = (unsigned)hv[4] | ((unsigned)hv[5] << 16);
  ho.w = (unsigned)hv[6] | ((unsigned)hv[7] << 16);
  lo4.x = (unsigned)lv[0] | ((unsigned)lv[1] << 16);
  lo4.y = (unsigned)lv[2] | ((unsigned)lv[3] << 16);
  lo4.z = (unsigned)lv[4] | ((unsigned)lv[5] << 16);
  lo4.w = (unsigned)lv[6] | ((unsigned)lv[7] << 16);
  *reinterpret_cast<uint4*>(&hi[(size_t)i * 8]) = ho;
  *reinterpret_cast<uint4*>(&lo[(size_t)i * 8]) = lo4;
}

// W[l] is [K=256][N=256] row-major; produce transposed single-fp16 Wt[n][k]
__global__ void k_wsplit(const float* __restrict__ W, unsigned short* __restrict__ Wf) {
  int i = blockIdx.x * 256 + threadIdx.x;  // i = n*256 + k
  int n = i >> 8, k = i & 255;
  Wf[i] = f2h(W[k * 256 + n]);
}

// ---------------- fp16 MFMA GEMM + fused el/er epilogue ----------------
// C[M,256] = (Ah + Al) @ Wf : 2 MFMA passes, 3 staged tensors.
// A = fp16 split (residual 2^-22); Wf single fp16 (error 2^-11, dominant).
// 128x128 tile, BK=32, 4 waves (2x2 of 64x64), round-9 grid (pair-swizzle 1D).
__global__ __launch_bounds__(256) void k_gemm_mfma(
    const unsigned short* __restrict__ Ahi, const unsigned short* __restrict__ Alo,
    const unsigned short* __restrict__ Bf,
    const float* __restrict__ al, const float* __restrict__ ar,
    unsigned short* __restrict__ h2, float* __restrict__ el, float* __restrict__ er,
    int M)
{
  const int id = blockIdx.x;
  const int cblk = (id >> 3) & 1;
  const int rblk = (id & 7) + 8 * (id >> 4);
  const int row0 = rblk * 128, col0 = cblk * 128;
  if (row0 >= M) return;

  __shared__ unsigned short sAh[128 * 32];
  __shared__ unsigned short sAl[128 * 32];
  __shared__ unsigned short sBf[128 * 32];
  const int tid = threadIdx.x;
  const int w = tid >> 6, lane = tid & 63;
  const int wr = w >> 1, wc = w & 1;

  f32x4 acc[4][4];
#pragma unroll
  for (int i = 0; i < 4; ++i)
#pragma unroll
    for (int j = 0; j < 4; ++j) acc[i][j] = (f32x4)0.0f;

  const int l15 = lane & 15;
  const int lq = lane >> 4;
  const int lk = lq * 8;

  for (int step = 0; step < 8; ++step) {
    const int k0 = step * 32;
    __syncthreads();
#pragma unroll
    for (int i = 0; i < 2; ++i) {
      const int u = i * 256 + tid;          // unit index 0..511
      const int r = u >> 2, ku = u & 3;     // row 0..127, 16B chunk 0..3
      const int ubase = (i * 256 + w * 64) * 8;  // wave-uniform LDS elem base
      const int arow = min(row0 + r, M - 1);
      gld16(Ahi + (size_t)arow * F + k0 + ku * 8, &sAh[ubase]);
      gld16(Alo + (size_t)arow * F + k0 + ku * 8, &sAl[ubase]);
      gld16(Bf + (size_t)(col0 + r) * F + k0 + ku * 8, &sBf[ubase]);
    }
    __syncthreads();

    f16x8 ah[4], alv[4], bf[4];
#pragma unroll
    for (int f = 0; f < 4; ++f) {
      const int ra = (wr * 64 + f * 16 + l15) * 32 + lk;
      const int rb = (wc * 64 + f * 16 + l15) * 32 + lk;
      ah[f]  = *reinterpret_cast<const f16x8*>(&sAh[ra]);
      alv[f] = *reinterpret_cast<const f16x8*>(&sAl[ra]);
      bf[f]  = *reinterpret_cast<const f16x8*>(&sBf[rb]);
    }
#pragma unroll
    for (int fr = 0; fr < 4; ++fr)
#pragma unroll
      for (int fc = 0; fc < 4; ++fc) {
        acc[fr][fc] = __builtin_amdgcn_mfma_f32_16x16x32_f16(ah[fr], bf[fc], acc[fr][fc], 0, 0, 0);
        acc[fr][fc] = __builtin_amdgcn_mfma_f32_16x16x32_f16(alv[fr], bf[fc], acc[fr][fc], 0, 0, 0);
      }
  }

  // ---- h2 (fp16, row-major) store ----
#pragma unroll
  for (int fr = 0; fr < 4; ++fr) {
#pragma unroll
    for (int r = 0; r < 4; ++r) {
      const int grow = row0 + wr * 64 + fr * 16 + lq * 4 + r;
      if (grow < M) {
#pragma unroll
        for (int fc = 0; fc < 4; ++fc)
          h2[(size_t)grow * F + col0 + wc * 64 + fc * 16 + l15] = f2h(acc[fr][fc][r]);
      }
    }
  }

  // ---- fused el/er: exact f32 dot with al/ar over this wave's 64 cols (2 heads) ----
  float alc[4], arc[4];
#pragma unroll
  for (int fc = 0; fc < 4; ++fc) {
    const int cg = col0 + wc * 64 + fc * 16 + l15;
    alc[fc] = al[cg];
    arc[fc] = ar[cg];
  }
  const int hb = (col0 + wc * 64) >> 5;
#pragma unroll
  for (int fr = 0; fr < 4; ++fr) {
#pragma unroll
    for (int r = 0; r < 4; ++r) {
      float e0 = acc[fr][0][r] * alc[0] + acc[fr][1][r] * alc[1];
      float e1 = acc[fr][2][r] * alc[2] + acc[fr][3][r] * alc[3];
      float f0 = acc[fr][0][r] * arc[0] + acc[fr][1][r] * arc[1];
      float f1 = acc[fr][2][r] * arc[2] + acc[fr][3][r] * arc[3];
#pragma unroll
      for (int d = 1; d < 16; d <<= 1) {
        e0 += __shfl_xor(e0, d, 64);
        e1 += __shfl_xor(e1, d, 64);
        f0 += __shfl_xor(f0, d, 64);
        f1 += __shfl_xor(f1, d, 64);
      }
      const int n = row0 + wr * 64 + fr * 16 + lq * 4 + r;
      if (l15 == 0 && n < M) {
        el[n * 8 + hb] = e0;
        el[n * 8 + hb + 1] = e1;
        er[n * 8 + hb] = f0;
        er[n * 8 + hb + 1] = f1;
      }
    }
  }
}

// ---------------- fused aggregation: one wave per dst node, single edge pass ----
// (round-6 structure: ~82us, ~20% above the measured L2-miss fabric floor; done)
__global__ __launch_bounds__(512) void k_agg(
    const unsigned short* __restrict__ h2, const float* __restrict__ el,
    const float* __restrict__ er, const int* __restrict__ off,
    const int* __restrict__ csr_src, const float* __restrict__ bias,
    float* __restrict__ yf, unsigned short* __restrict__ yhi,
    unsigned short* __restrict__ ylo, int mode)  // mode 0: fp16 hi/lo + leaky; 1: f32 final
{
  __shared__ float a_lds[8][64][9];  // pad 8->9: conflict-free write & read
  __shared__ int s_lds[8][64];
  const int wave = threadIdx.x >> 6;
  const int lane = threadIdx.x & 63;
  const int n = blockIdx.x * 8 + wave;
  if (n >= NN) return;
  const int o0 = off[n], o1 = off[n + 1];

  float ern[8];
  {
    const float4 e0 = *reinterpret_cast<const float4*>(&er[n * 8]);
    const float4 e1 = *reinterpret_cast<const float4*>(&er[n * 8 + 4]);
    ern[0] = e0.x; ern[1] = e0.y; ern[2] = e0.z; ern[3] = e0.w;
    ern[4] = e1.x; ern[5] = e1.y; ern[6] = e1.z; ern[7] = e1.w;
  }
  const int c0 = lane * 4;
  const int myh = lane >> 3;
  float asum = 0.f;  // per-lane sum of exp for head myh (all edges)
  float4 acc0 = make_float4(0.f, 0.f, 0.f, 0.f), acc1 = acc0, acc2 = acc0, acc3 = acc0;

  for (int start = o0; start < o1; start += 64) {
    const int idx = start + lane;
    if (idx < o1) {
      const int s = csr_src[idx];
      s_lds[wave][lane] = s;
      const float4 e0 = *reinterpret_cast<const float4*>(&el[s * 8]);
      const float4 e1 = *reinterpret_cast<const float4*>(&el[s * 8 + 4]);
      float ev[8] = {e0.x, e0.y, e0.z, e0.w, e1.x, e1.y, e1.z, e1.w};
#pragma unroll
      for (int t = 0; t < 8; ++t) {
        float e = ev[t] + ern[t];
        e = e > 0.f ? e : 0.2f * e;
        a_lds[wave][lane][t] = __expf(e);
      }
    }
    // same-wave LDS RAW ordering
    asm volatile("s_waitcnt lgkmcnt(0)" ::: "memory");
    __builtin_amdgcn_sched_barrier(0);
    const int cnt = min(64, o1 - start);
    int k = 0;
    for (; k + 8 <= cnt; k += 8) {
      const int s0 = s_lds[wave][k + 0], s1 = s_lds[wave][k + 1];
      const int s2 = s_lds[wave][k + 2], s3 = s_lds[wave][k + 3];
      const int s4 = s_lds[wave][k + 4], s5 = s_lds[wave][k + 5];
      const int s6 = s_lds[wave][k + 6], s7 = s_lds[wave][k + 7];
      const float a0 = a_lds[wave][k + 0][myh], a1 = a_lds[wave][k + 1][myh];
      const float a2 = a_lds[wave][k + 2][myh], a3 = a_lds[wave][k + 3][myh];
      const float a4 = a_lds[wave][k + 4][myh], a5 = a_lds[wave][k + 5][myh];
      const float a6 = a_lds[wave][k + 6][myh], a7 = a_lds[wave][k + 7][myh];
      const float4 h0 = ld_h4(&h2[(size_t)s0 * F + c0]);
      const float4 h1 = ld_h4(&h2[(size_t)s1 * F + c0]);
      const float4 h2v = ld_h4(&h2[(size_t)s2 * F + c0]);
      const float4 h3 = ld_h4(&h2[(size_t)s3 * F + c0]);
      const float4 h4 = ld_h4(&h2[(size_t)s4 * F + c0]);
      const float4 h5 = ld_h4(&h2[(size_t)s5 * F + c0]);
      const float4 h6 = ld_h4(&h2[(size_t)s6 * F + c0]);
      const float4 h7 = ld_h4(&h2[(size_t)s7 * F + c0]);
      asum += ((a0 + a1) + (a2 + a3)) + ((a4 + a5) + (a6 + a7));
      acc0.x = fmaf(a0, h0.x, acc0.x); acc0.y = fmaf(a0, h0.y, acc0.y);
      acc0.z = fmaf(a0, h0.z, acc0.z); acc0.w = fmaf(a0, h0.w, acc0.w);
      acc1.x = fmaf(a1, h1.x, acc1.x); acc1.y = fmaf(a1, h1.y, acc1.y);
      acc1.z = fmaf(a1, h1.z, acc1.z); acc1.w = fmaf(a1, h1.w, acc1.w);
      acc2.x = fmaf(a2, h2v.x, acc2.x); acc2.y = fmaf(a2, h2v.y, acc2.y);
      acc2.z = fmaf(a2, h2v.z, acc2.z); acc2.w = fmaf(a2, h2v.w, acc2.w);
      acc3.x = fmaf(a3, h3.x, acc3.x); acc3.y = fmaf(a3, h3.y, acc3.y);
      acc3.z = fmaf(a3, h3.z, acc3.z); acc3.w = fmaf(a3, h3.w, acc3.w);
      acc0.x = fmaf(a4, h4.x, acc0.x); acc0.y = fmaf(a4, h4.y, acc0.y);
      acc0.z = fmaf(a4, h4.z, acc0.z); acc0.w = fmaf(a4, h4.w, acc0.w);
      acc1.x = fmaf(a5, h5.x, acc1.x); acc1.y = fmaf(a5, h5.y, acc1.y);
      acc1.z = fmaf(a5, h5.z, acc1.z); acc1.w = fmaf(a5, h5.w, acc1.w);
      acc2.x = fmaf(a6, h6.x, acc2.x); acc2.y = fmaf(a6, h6.y, acc2.y);
      acc2.z = fmaf(a6, h6.z, acc2.z); acc2.w = fmaf(a6, h6.w, acc2.w);
      acc3.x = fmaf(a7, h7.x, acc3.x); acc3.y = fmaf(a7, h7.y, acc3.y);
      acc3.z = fmaf(a7, h7.z, acc3.z); acc3.w = fmaf(a7, h7.w, acc3.w);
    }
    for (; k < cnt; ++k) {
      const int s = s_lds[wave][k];
      const float a = a_lds[wave][k][myh];
      const float4 hv = ld_h4(&h2[(size_t)s * F + c0]);
      asum += a;
      acc0.x = fmaf(a, hv.x, acc0.x); acc0.y = fmaf(a, hv.y, acc0.y);
      acc0.z = fmaf(a, hv.z, acc0.z); acc0.w = fmaf(a, hv.w, acc0.w);
    }
    __builtin_amdgcn_sched_barrier(0);
  }

  const float inv = asum > 0.f ? 1.f / asum : 0.f;

  const float4 bv = *reinterpret_cast<const float4*>(&bias[c0]);
  float4 o;
  o.x = (acc0.x + acc1.x + acc2.x + acc3.x) * inv + bv.x;
  o.y = (acc0.y + acc1.y + acc2.y + acc3.y) * inv + bv.y;
  o.z = (acc0.z + acc1.z + acc2.z + acc3.z) * inv + bv.z;
  o.w = (acc0.w + acc1.w + acc2.w + acc3.w) * inv + bv.w;
  if (mode == 0) {
    o.x = o.x > 0.f ? o.x : 0.01f * o.x;
    o.y = o.y > 0.f ? o.y : 0.01f * o.y;
    o.z = o.z > 0.f ? o.z : 0.01f * o.z;
    o.w = o.w > 0.f ? o.w : 0.01f * o.w;
    unsigned short h0 = f2h(o.x), h1 = f2h(o.y), h2w = f2h(o.z), h3 = f2h(o.w);
    unsigned short l0 = f2h(o.x - h2f(h0)), l1 = f2h(o.y - h2f(h1));
    unsigned short l2 = f2h(o.z - h2f(h2w)), l3 = f2h(o.w - h2f(h3));
    uint2 hw, lw;
    hw.x = (unsigned)h0 | ((unsigned)h1 << 16); hw.y = (unsigned)h2w | ((unsigned)h3 << 16);
    lw.x = (unsigned)l0 | ((unsigned)l1 << 16); lw.y = (unsigned)l2 | ((unsigned)l3 << 16);
    *reinterpret_cast<uint2*>(&yhi[(size_t)n * F + c0]) = hw;
    *reinterpret_cast<uint2*>(&ylo[(size_t)n * F + c0]) = lw;
  } else {
    *reinterpret_cast<float4*>(&yf[(size_t)n * F + c0]) = o;
  }
}

extern "C" void kernel_launch(void* const* d_in, const int* in_sizes, int n_in,
                              void* d_out, int out_size, void* d_ws, size_t ws_size,
                              hipStream_t stream) {
  const float* x   = (const float*)d_in[0];
  const int*   src = (const int*)d_in[1];
  const int*   dst = (const int*)d_in[2];
  const float* W   = (const float*)d_in[3];
  const float* al  = (const float*)d_in[4];
  const float* ar  = (const float*)d_in[5];
  const float* b   = (const float*)d_in[6];
  float* out = (float*)d_out;

  char* ws = (char*)d_ws;
  auto take = [&](size_t bytes) {
    char* p = ws;
    ws += (bytes + 255) & ~(size_t)255;
    return p;
  };
  int*   off     = (int*)take((NN + 1) * sizeof(int));
  int*   counts  = (int*)take(NN * sizeof(int));
  int*   bsum    = (int*)take(256 * sizeof(int));
  int*   csr_src = (int*)take(NE * sizeof(int));
  float* el      = (float*)take((size_t)NN * NHEADS * sizeof(float));
  float* er      = (float*)take((size_t)NN * NHEADS * sizeof(float));
  unsigned short* h2    = (unsigned short*)take((size_t)NN * F * 2);
  unsigned short* A_hi  = (unsigned short*)take((size_t)NN * F * 2);
  unsigned short* A_lo  = (unsigned short*)take((size_t)NN * F * 2);
  unsigned short* Wt_f  = (unsigned short*)take((size_t)F * F * 2);

  // CSR build
  const int NB = (NN + 255) / 256;  // 196
  k_zero_int<<<NB, 256, 0, stream>>>(counts, NN);
  k_hist<<<(NE + 255) / 256, 256, 0, stream>>>(dst, counts, NE);
  k_blocksum<<<NB, 256, 0, stream>>>(counts, bsum, NN);
  k_scan_bsums<<<1, 256, 0, stream>>>(bsum, off, NB, NN);
  k_scan_final<<<NB, 256, 0, stream>>>(counts, bsum, off, NN);
  k_scatter<<<(NE + 255) / 256, 256, 0, stream>>>(src, dst, off, counts, csr_src, NE);

  const int n8 = NN * F / 8;
  k_split<<<(n8 + 255) / 256, 256, 0, stream>>>(x, A_hi, A_lo, n8);
  // 1D pair-swizzled grid: 391 row-blocks x 2 col-blocks in groups of 16 ids
  const int nrblk = (NN + 127) / 128;            // 391
  const int ngemm = ((nrblk + 7) / 8) * 16;      // 784
  for (int l = 0; l < 3; ++l) {
    k_wsplit<<<256, 256, 0, stream>>>(W + (size_t)l * F * F, Wt_f);
    k_gemm_mfma<<<ngemm, 256, 0, stream>>>(
        A_hi, A_lo, Wt_f, al + l * F, ar + l * F, h2, el, er, NN);
    // layers 0,1: write next-layer fp16 hi/lo input; layer 2: final f32 to d_out
    k_agg<<<(NN + 7) / 8, 512, 0, stream>>>(h2, el, er, off, csr_src, b + (size_t)l * F,
                                            out, A_hi, A_lo, (l < 2) ? 0 : 1);
  }
}